// Round 3
// baseline (22804.205 us; speedup 1.0000x reference)
//
#include <hip/hip_runtime.h>
#include <cstdint>
#include <cstddef>

typedef __bf16 bf16x8 __attribute__((ext_vector_type(8)));
typedef float  f32x4  __attribute__((ext_vector_type(4)));

#define MFMA16(a, b, c) __builtin_amdgcn_mfma_f32_16x16x32_bf16((a), (b), (c), 0, 0, 0)

__device__ __forceinline__ float sigm(float x) {
    return 1.f / (1.f + __expf(-x));
}
__device__ __forceinline__ float tanh_(float x) {
    // tanh(x) = 1 - 2/(e^{2x}+1); expf overflow -> inf -> 1/inf=0 -> 1 (graceful)
    return 1.f - 2.f / (__expf(2.f * x) + 1.f);
}

// ---------------------------------------------------------------------------
// Repack the four H-recurrence weight matrices (256x256 fp32, W[k][h]) into
// bf16 MFMA B-fragment order for 16x16x32_bf16 (verified end-to-end round 2):
//   o = ((nt*8 + kb)*64 + lane)*8 + j ;  n = nt*16+(lane&15) = g*256+h ;
//   k = kb*32 + (lane>>4)*8 + j
// Block j of a group reads n-tiles nt = g*16 + j  (h = 16j + col).
// Also zeroes the sync flags (poisoned 0xAA by the harness each call).
// ---------------------------------------------------------------------------
__global__ void prep_wh(const float* __restrict__ Wf, const float* __restrict__ Wp,
                        const float* __restrict__ Wt, const float* __restrict__ Wo,
                        __bf16* __restrict__ out, unsigned int* __restrict__ flags) {
    if (blockIdx.x == 0 && threadIdx.x < 256) flags[threadIdx.x] = 0u;
    int o  = blockIdx.x * 256 + threadIdx.x;   // 262144 total
    int j  = o & 7;
    int l  = (o >> 3) & 63;
    int kb = (o >> 9) & 7;
    int nt = o >> 12;                          // 0..63
    int n  = nt * 16 + (l & 15);
    int g  = n >> 8, h = n & 255;
    int k  = kb * 32 + (l >> 4) * 8 + j;       // 0..255
    const float* W = (g == 0) ? Wf : (g == 1) ? Wp : (g == 2) ? Wt : Wo;
    out[o] = (__bf16)W[k * 256 + h];
}

// Same for the x-projection weights (128x256), K=128 -> kb 0..3
__global__ void prep_wx(const float* __restrict__ Wf, const float* __restrict__ Wp,
                        const float* __restrict__ Wt, const float* __restrict__ Wo,
                        __bf16* __restrict__ out) {
    int o  = blockIdx.x * 256 + threadIdx.x;   // 131072 total
    int j  = o & 7;
    int l  = (o >> 3) & 63;
    int kb = (o >> 9) & 3;
    int nt = o >> 11;                          // 0..63
    int n  = nt * 16 + (l & 15);
    int g  = n >> 8, h = n & 255;
    int k  = kb * 32 + (l >> 4) * 8 + j;       // 0..127
    const float* W = (g == 0) ? Wf : (g == 1) ? Wp : (g == 2) ? Wt : Wo;
    out[o] = (__bf16)W[k * 256 + h];
}

// ---------------------------------------------------------------------------
// Cooperative recurrence, single launch for all T=1024 steps.
// 16 groups x 16 blocks. Group grp = blockIdx.x & 15 (same-XCD heuristic),
// block-in-group j = blockIdx.x >> 4. Group handles batch rows [16grp,16grp+16).
// Block j handles h in [16j, 16j+16) for all 4 gates; wave g = gate g = one
// 16x16 MFMA N-tile (nt = g*16 + j). Per wave per step: 4 x-part MFMAs (K=128)
// + 8 h-part MFMAs (K=256), M=16 real batch rows -- no M padding.
// Cross-block state exchange: double-buffered global short buffer
// sbufG[2][16 grp][16 m][256 k] (bf16) + per-block monotonic flags, agent-scope
// release/acquire atomics. Thread tid = (m = tid>>4, h = tid&15) owns that
// cell's (short,long) fp32 state in registers for the whole run.
// Flag protocol: flag[grp*16+j] = 1 + (global steps published by block j);
// step t polls all 16 group flags >= t+1, reads parity (t+1)&1, writes parity
// t&1, publishes t+2. Entering step t+1 implies all blocks finished reading
// parity (t-1)&1 -> ping-pong WAR-safe.
// ---------------------------------------------------------------------------
__global__ __launch_bounds__(256, 1) void recur_sync(
        const float* __restrict__ x,
        const __bf16* __restrict__ whfrag, const __bf16* __restrict__ wxfrag,
        const float* __restrict__ bfv, const float* __restrict__ bpv,
        const float* __restrict__ btv, const float* __restrict__ bov,
        unsigned int* __restrict__ flags, __bf16* __restrict__ sbufG,
        float* __restrict__ out) {
    __shared__ float zbuf[1024];      // [g][lq*16+lm]*4+r
    __shared__ float bbuf[4][16];

    const int tid = threadIdx.x, wv = tid >> 6, l = tid & 63;
    const int lm = l & 15, lq = l >> 4;
    const int grp = blockIdx.x & 15, j = blockIdx.x >> 4;
    const int m = tid >> 4, h = tid & 15;

    // resident weight fragments: this wave's N-tile (nt = wv*16 + j)
    const bf16x8* whf = reinterpret_cast<const bf16x8*>(whfrag);
    const bf16x8* wxf = reinterpret_cast<const bf16x8*>(wxfrag);
    const int nt = wv * 16 + j;
    bf16x8 wh[8], wx[4];
#pragma unroll
    for (int kb = 0; kb < 8; kb++) wh[kb] = whf[(nt * 8 + kb) * 64 + l];
#pragma unroll
    for (int kb = 0; kb < 4; kb++) wx[kb] = wxf[(nt * 4 + kb) * 64 + l];

    // biases for this block's 64 gate outputs
    if (tid < 64) {
        int g = tid >> 4, hh = tid & 15;
        const float* bsrc = (g == 0) ? bfv : (g == 1) ? bpv : (g == 2) ? btv : bov;
        bbuf[g][hh] = bsrc[j * 16 + hh];
    }

    // init state (zeros) -> publish into parity-1 buffer with flag = 1
    float shortv = 0.f, longv = 0.f;
    sbufG[((size_t)(1 * 16 + grp)) * 4096 + m * 256 + j * 16 + h] = (__bf16)0.f;
    __syncthreads();
    if (tid == 0) {
        __threadfence();
        __hip_atomic_store(&flags[grp * 16 + j], 1u,
                           __ATOMIC_RELEASE, __HIP_MEMORY_SCOPE_AGENT);
    }

    const float* xrow = x + (size_t)(grp * 16 + lm) * 1024 * 128;
    unsigned int* const gflags = flags + grp * 16;

    for (int t = 0; t < 1024; t++) {
        // ---- x-part: fp32 x -> bf16 A-frags, 4 MFMAs (no sync dependency) ----
        f32x4 accx = {0.f, 0.f, 0.f, 0.f};
#pragma unroll
        for (int kb = 0; kb < 4; kb++) {
            const float* src = xrow + (size_t)t * 128 + kb * 32 + lq * 8;
            float4 v0 = *reinterpret_cast<const float4*>(src);
            float4 v1 = *reinterpret_cast<const float4*>(src + 4);
            bf16x8 a;
            a[0] = (__bf16)v0.x; a[1] = (__bf16)v0.y; a[2] = (__bf16)v0.z; a[3] = (__bf16)v0.w;
            a[4] = (__bf16)v1.x; a[5] = (__bf16)v1.y; a[6] = (__bf16)v1.z; a[7] = (__bf16)v1.w;
            accx = MFMA16(a, wx[kb], accx);
        }

        // ---- wait for all 16 blocks' state t-1 (every lane polls, 4x redundant) ----
        {
            const unsigned target = (unsigned)(t + 1);
            long spins = 0;
            while (__hip_atomic_load(&gflags[lm], __ATOMIC_ACQUIRE,
                                     __HIP_MEMORY_SCOPE_AGENT) < target) {
                __builtin_amdgcn_s_sleep(1);
                if (++spins > (1L << 24)) break;   // bounded: wrong > hung
            }
        }

        // ---- h-part: short A-frags from global ping-pong buffer, 8 MFMAs ----
        const __bf16* sb = sbufG + ((size_t)(((t + 1) & 1) * 16 + grp)) * 4096
                                 + (size_t)lm * 256;
        f32x4 acch = {0.f, 0.f, 0.f, 0.f};
#pragma unroll
        for (int kb = 0; kb < 8; kb++) {
            bf16x8 a = *reinterpret_cast<const bf16x8*>(sb + kb * 32 + lq * 8);
            acch = MFMA16(a, wh[kb], acch);
        }

        // ---- exchange z across the 4 gate-waves via LDS ----
        f32x4 z = accx + acch;
        *reinterpret_cast<f32x4*>(&zbuf[(wv * 64 + lq * 16 + lm) * 4]) = z;
        __syncthreads();

        // ---- elementwise recurrence: thread = (batch row m, hidden h) ----
        const int zb = ((m >> 2) * 16 + h) * 4 + (m & 3);
        float z0 = zbuf[zb]       + bbuf[0][h];
        float z1 = zbuf[256 + zb] + bbuf[1][h];
        float z2 = zbuf[512 + zb] + bbuf[2][h];
        float z3 = zbuf[768 + zb] + bbuf[3][h];
        float fg  = sigm(z0);
        float pg  = sigm(z1);
        float ptg = tanh_(z2);
        float og  = sigm(z3);
        longv  = fg * longv + pg * ptg;
        shortv = tanh_(longv) * og;

        // publish new short into parity t&1
        sbufG[((size_t)((t & 1) * 16 + grp)) * 4096 + m * 256 + j * 16 + h] =
            (__bf16)shortv;
        __syncthreads();   // all stores issued (+ zbuf safe for next step)
        if (tid == 0) {
            __threadfence();
            __hip_atomic_store(&flags[grp * 16 + j], (unsigned)(t + 2),
                               __ATOMIC_RELEASE, __HIP_MEMORY_SCOPE_AGENT);
        }
    }

    const int b = grp * 16 + m;
    out[b * 256 + j * 16 + h]         = shortv;   // short
    out[65536 + b * 256 + j * 16 + h] = longv;    // long
}

// ---------------------------------------------------------------------------
extern "C" void kernel_launch(void* const* d_in, const int* in_sizes, int n_in,
                              void* d_out, int out_size, void* d_ws, size_t ws_size,
                              hipStream_t stream) {
    const float* x   = (const float*)d_in[0];
    const float* Wfh = (const float*)d_in[1];
    const float* Wfx = (const float*)d_in[2];
    const float* bf_ = (const float*)d_in[3];
    const float* Wph = (const float*)d_in[4];
    const float* Wpx = (const float*)d_in[5];
    const float* bp_ = (const float*)d_in[6];
    const float* Wth = (const float*)d_in[7];
    const float* Wtx = (const float*)d_in[8];
    const float* bt_ = (const float*)d_in[9];
    const float* Woh = (const float*)d_in[10];
    const float* Wox = (const float*)d_in[11];
    const float* bo_ = (const float*)d_in[12];
    float* out = (float*)d_out;

    // workspace layout (~1.06 MB total)
    char* wsb = (char*)d_ws;
    __bf16*       whfrag = (__bf16*)wsb;                      // 512 KB
    __bf16*       wxfrag = (__bf16*)(wsb + 524288);           // 256 KB
    __bf16*       sbufG  = (__bf16*)(wsb + 786432);           // 256 KB (2x16x16x256)
    unsigned int* flags  = (unsigned int*)(wsb + 1048576);    //   1 KB

    prep_wh<<<1024, 256, 0, stream>>>(Wfh, Wph, Wth, Woh, whfrag, flags);
    prep_wx<<<512, 256, 0, stream>>>(Wfx, Wpx, Wtx, Wox, wxfrag);

    recur_sync<<<256, 256, 0, stream>>>(
        x, whfrag, wxfrag, bf_, bp_, bt_, bo_, flags, sbufG, out);
}

// Round 5
// 2864.315 us; speedup vs baseline: 7.9615x; 7.9615x over previous
//
#include <hip/hip_runtime.h>
#include <cstdint>
#include <cstddef>

typedef __bf16 bf16x8 __attribute__((ext_vector_type(8)));
typedef __bf16 bf16x4 __attribute__((ext_vector_type(4)));
typedef float  f32x4  __attribute__((ext_vector_type(4)));

// intrinsic MFMA for the xproj GEMM (compiler-scheduled)
#define MFMA16(a, b, c) __builtin_amdgcn_mfma_f32_16x16x32_bf16((a), (b), (c), 0, 0, 0)

// ---------------------------------------------------------------------------
// Self-contained MFMA chain asm blocks for the recurrence.
//  - SrcC of the first MFMA is a loop-invariant zero register (zz): no
//    VALU-init -> MFMA SrcC hazard inside the loop.
//  - All MFMAs of a chain live in ONE asm block: the scheduler cannot break
//    intra-chain ordering.
//  - Trailing s_nop 7 x2 INSIDE the block: any subsequent reader of the
//    accumulator is >=16 cycles after the last MFMA (dst-write hazard safe).
//  - "=&v" early-clobber: accumulators can never alias a/w/zz inputs.
// CH2: two interleaved 8-step chains (tiles t,t+1). CH1: one 8-step chain.
// ---------------------------------------------------------------------------
#define MF "v_mfma_f32_16x16x32_bf16 "
#define CH2_BODY \
    MF "%0, %2, %10, %26\n\t"  MF "%1, %2, %18, %26\n\t" \
    MF "%0, %3, %11, %0\n\t"   MF "%1, %3, %19, %1\n\t"  \
    MF "%0, %4, %12, %0\n\t"   MF "%1, %4, %20, %1\n\t"  \
    MF "%0, %5, %13, %0\n\t"   MF "%1, %5, %21, %1\n\t"  \
    MF "%0, %6, %14, %0\n\t"   MF "%1, %6, %22, %1\n\t"  \
    MF "%0, %7, %15, %0\n\t"   MF "%1, %7, %23, %1\n\t"  \
    MF "%0, %8, %16, %0\n\t"   MF "%1, %8, %24, %1\n\t"  \
    MF "%0, %9, %17, %0\n\t"   MF "%1, %9, %25, %1\n\t"  \
    "s_nop 7\n\ts_nop 7"
#define CH1_BODY \
    MF "%0, %1, %9,  %17\n\t" \
    MF "%0, %2, %10, %0\n\t"  \
    MF "%0, %3, %11, %0\n\t"  \
    MF "%0, %4, %12, %0\n\t"  \
    MF "%0, %5, %13, %0\n\t"  \
    MF "%0, %6, %14, %0\n\t"  \
    MF "%0, %7, %15, %0\n\t"  \
    MF "%0, %8, %16, %0\n\t"  \
    "s_nop 7\n\ts_nop 7"

#define A8(aa)  "v"((aa)[0]), "v"((aa)[1]), "v"((aa)[2]), "v"((aa)[3]), \
                "v"((aa)[4]), "v"((aa)[5]), "v"((aa)[6]), "v"((aa)[7])
#define W8A(W)  "a"((W)[0]), "a"((W)[1]), "a"((W)[2]), "a"((W)[3]), \
                "a"((W)[4]), "a"((W)[5]), "a"((W)[6]), "a"((W)[7])
#define W8V(W)  "v"((W)[0]), "v"((W)[1]), "v"((W)[2]), "v"((W)[3]), \
                "v"((W)[4]), "v"((W)[5]), "v"((W)[6]), "v"((W)[7])

#define CHAIN2A(c0, c1, W0, W1) \
    asm(CH2_BODY : "=&v"(c0), "=&v"(c1) : A8(a), W8A(W0), W8A(W1), "v"(zz))
#define CHAIN2V(c0, c1, W0, W1) \
    asm(CH2_BODY : "=&v"(c0), "=&v"(c1) : A8(a), W8V(W0), W8V(W1), "v"(zz))
#define CHAIN1V(c0, W) \
    asm(CH1_BODY : "=&v"(c0) : A8(a), W8V(W), "v"(zz))

__device__ __forceinline__ float sigm(float x) {
    return 1.f / (1.f + __expf(-x));
}
__device__ __forceinline__ float tanh_(float x) {
    // tanh(x) = 1 - 2/(e^{2x}+1); expf overflow -> inf -> 1/inf=0 -> 1 (graceful)
    return 1.f - 2.f / (__expf(2.f * x) + 1.f);
}

// ---------------------------------------------------------------------------
// Repack the four H-recurrence weights (256x256 fp32, W[k][h]) into bf16 MFMA
// B-fragment order for 16x16x32_bf16 (layout verified end-to-end round 2):
//   o = ((nt*8 + kb)*64 + lane)*8 + j ;  n = nt*16+(lane&15) = g*256+h ;
//   k = kb*32 + (lane>>4)*8 + j
// ---------------------------------------------------------------------------
__global__ void prep_wh(const float* __restrict__ Wf, const float* __restrict__ Wp,
                        const float* __restrict__ Wt, const float* __restrict__ Wo,
                        __bf16* __restrict__ out) {
    int o  = blockIdx.x * 256 + threadIdx.x;   // 262144 total
    int j  = o & 7;
    int l  = (o >> 3) & 63;
    int kb = (o >> 9) & 7;
    int nt = o >> 12;                          // 0..63
    int n  = nt * 16 + (l & 15);
    int g  = n >> 8, h = n & 255;
    int k  = kb * 32 + (l >> 4) * 8 + j;       // 0..255
    const float* W = (g == 0) ? Wf : (g == 1) ? Wp : (g == 2) ? Wt : Wo;
    out[o] = (__bf16)W[k * 256 + h];
}

// Same for the x-projection weights (128x256), K=128 -> kb 0..3
__global__ void prep_wx(const float* __restrict__ Wf, const float* __restrict__ Wp,
                        const float* __restrict__ Wt, const float* __restrict__ Wo,
                        __bf16* __restrict__ out) {
    int o  = blockIdx.x * 256 + threadIdx.x;   // 131072 total
    int j  = o & 7;
    int l  = (o >> 3) & 63;
    int kb = (o >> 9) & 3;
    int nt = o >> 11;                          // 0..63
    int n  = nt * 16 + (l & 15);
    int g  = n >> 8, h = n & 255;
    int k  = kb * 32 + (l >> 4) * 8 + j;       // 0..127
    const float* W = (g == 0) ? Wf : (g == 1) ? Wp : (g == 2) ? Wt : Wo;
    out[o] = (__bf16)W[k * 256 + h];
}

// ---------------------------------------------------------------------------
// Chunked x-projection GEMM. Chunk c covers time steps [c*Tc, (c+1)*Tc).
// Row r = b*Tc + tc. Output TRANSPOSED per row: XP[r][h*4 + g] (bf16, bias
// included) so recur thread h reads its 4 gate values as one 8-byte load.
// ---------------------------------------------------------------------------
__global__ __launch_bounds__(256) void xproj_gemm(
        const float* __restrict__ x, const __bf16* __restrict__ wxfrag,
        const float* __restrict__ bf, const float* __restrict__ bp,
        const float* __restrict__ bt, const float* __restrict__ bo,
        __bf16* __restrict__ xp, int Tc, int tcsh, int chunk) {
    __shared__ __align__(16) __bf16 As[128 * 128];   // 32 KB
    const int tid = threadIdx.x;
    const int m0  = blockIdx.x * 128;
    const int by  = blockIdx.y;                      // 0..7 (N-tile of 128)
    const int c0  = chunk * Tc;

    // stage A: 128 chunk-rows x 128 cols, fp32 -> bf16
#pragma unroll
    for (int i = 0; i < 16; i++) {
        int f   = i * 256 + tid;
        int row = f >> 5;
        int c4  = (f & 31) * 4;
        int r   = m0 + row;
        int b   = r >> tcsh;
        int tc  = r & (Tc - 1);
        float4 v = *reinterpret_cast<const float4*>(
            x + ((size_t)b * 1024 + (size_t)(c0 + tc)) * 128 + c4);
        __bf16 w0 = (__bf16)v.x, w1 = (__bf16)v.y, w2 = (__bf16)v.z, w3 = (__bf16)v.w;
        bf16x4 w = {w0, w1, w2, w3};
        *reinterpret_cast<bf16x4*>(&As[row * 128 + c4]) = w;
    }
    __syncthreads();

    const int wv = tid >> 6, l = tid & 63, lm = l & 15, lk = l >> 4;
    const bf16x8* bfr = reinterpret_cast<const bf16x8*>(wxfrag);

    f32x4 acc[2][8];
#pragma unroll
    for (int a = 0; a < 2; a++)
#pragma unroll
        for (int c = 0; c < 8; c++) acc[a][c] = (f32x4){0.f, 0.f, 0.f, 0.f};

#pragma unroll
    for (int kb = 0; kb < 4; kb++) {
        bf16x8 afr[2];
#pragma unroll
        for (int tr = 0; tr < 2; tr++)
            afr[tr] = *reinterpret_cast<const bf16x8*>(
                &As[(wv * 32 + tr * 16 + lm) * 128 + kb * 32 + lk * 8]);
#pragma unroll
        for (int tc = 0; tc < 8; tc++) {
            int nt = by * 8 + tc;
            bf16x8 bq = bfr[(nt * 4 + kb) * 64 + l];
            acc[0][tc] = MFMA16(afr[0], bq, acc[0][tc]);
            acc[1][tc] = MFMA16(afr[1], bq, acc[1][tc]);
        }
    }

    const int g = by >> 1;
    const float* bias = (g == 0) ? bf : (g == 1) ? bp : (g == 2) ? bt : bo;
#pragma unroll
    for (int tc = 0; tc < 8; tc++) {
        int n   = by * 128 + tc * 16 + lm;
        float bv = bias[n & 255];
        int h4g = (n & 255) * 4 + (n >> 8);          // transposed column
#pragma unroll
        for (int tr = 0; tr < 2; tr++) {
#pragma unroll
            for (int r = 0; r < 4; r++) {
                int row = m0 + wv * 32 + tr * 16 + lk * 4 + r;
                xp[(size_t)row * 1024 + h4g] = (__bf16)(acc[tr][tc][r] + bv);
            }
        }
    }
}

// ---------------------------------------------------------------------------
// Persistent recurrence over one time chunk. 256 blocks (1 batch row / CU),
// 256 threads (4 waves, 1/SIMD). Wave g = gate g = 16 N-tiles:
//   tiles 0..7  : weights in AGPRs (256/lane), "a" asm operands
//   tiles 8..11 : weights in VGPRs (128/lane), "v" asm operands
//   tiles 12..15: weights in LDS (128 KB), staged 1 tile at a time,
//                 interleaved with the AGPR chains to hide ds_read latency.
// M=1-padded MFMA: A = short broadcast to all 16 M-rows; D row 0 real.
// XP loads software-pipelined one step ahead.
// ---------------------------------------------------------------------------
__global__ __launch_bounds__(256, 1) void recur(
        const __bf16* __restrict__ xp, const __bf16* __restrict__ whfrag,
        float* __restrict__ state_s, float* __restrict__ state_l,
        float* __restrict__ out, int Tc, int tcsh, int first, int last) {
    __shared__ __align__(16) bf16x8 wlds[4 * 4 * 8 * 64];   // 131072 B
    __shared__ float  zbuf[1024];                           //   4096 B
    __shared__ __bf16 sbuf[256];                            //    512 B

    const int tid = threadIdx.x, wv = tid >> 6, l = tid & 63, lk = l >> 4;
    const int b = blockIdx.x;
    const bf16x8* wf = reinterpret_cast<const bf16x8*>(whfrag);

    // AGPR weight tiles 0..7 (64 frags = 256 AGPRs/lane)
    bf16x8 wa[8][8];
#pragma unroll
    for (int t = 0; t < 8; t++)
#pragma unroll
        for (int kb = 0; kb < 8; kb++)
            wa[t][kb] = wf[((wv * 16 + t) * 8 + kb) * 64 + l];
    // VGPR weight tiles 8..11 (32 frags = 128 VGPRs/lane)
    bf16x8 wr[4][8];
#pragma unroll
    for (int t = 0; t < 4; t++)
#pragma unroll
        for (int kb = 0; kb < 8; kb++)
            wr[t][kb] = wf[((wv * 16 + 8 + t) * 8 + kb) * 64 + l];
    // LDS weight tiles 12..15
#pragma unroll
    for (int t = 0; t < 4; t++)
#pragma unroll
        for (int kb = 0; kb < 8; kb++)
            wlds[((wv * 4 + t) * 8 + kb) * 64 + l] =
                wf[((wv * 16 + 12 + t) * 8 + kb) * 64 + l];

    float shortv, longv;
    if (first) { shortv = 0.f; longv = 0.f; }
    else       { shortv = state_s[(b << 8) + tid]; longv = state_l[(b << 8) + tid]; }
    sbuf[tid] = (__bf16)shortv;
    __syncthreads();

    const bf16x8* wldsw = wlds + (size_t)wv * 4 * 8 * 64;
    float* zb = zbuf + wv * 256;
    const __bf16* xpt = xp + ((size_t)b << (tcsh + 10)) + tid * 4;

    const f32x4 zz = {0.f, 0.f, 0.f, 0.f};   // loop-invariant SrcC zero

    // prefetch step 0
    bf16x4 xv = *reinterpret_cast<const bf16x4*>(xpt);

#define STAGE(lt) \
    _Pragma("unroll") for (int kb = 0; kb < 8; kb++) lw[kb] = wldsw[((lt) * 8 + kb) * 64 + l];

    for (int t = 0; t < Tc; t++) {
        // A-fragments: broadcast short into every M-row
        bf16x8 a[8];
#pragma unroll
        for (int kb = 0; kb < 8; kb++)
            a[kb] = *reinterpret_cast<const bf16x8*>(&sbuf[kb * 32 + lk * 8]);

        // prefetch next step's XP (consumed next iteration)
        int tn = (t + 1 < Tc) ? t + 1 : t;
        bf16x4 xn = *reinterpret_cast<const bf16x4*>(xpt + (size_t)tn * 1024);

        bf16x8 lw[8];
        f32x4 c0, c1;

        STAGE(0)
        CHAIN2A(c0, c1, wa[0], wa[1]);
        if (l < 16) { zb[0 * 16 + l] = c0[0]; zb[1 * 16 + l] = c1[0]; }
        CHAIN1V(c0, lw);                               // tile 12
        if (l < 16) zb[12 * 16 + l] = c0[0];

        STAGE(1)
        CHAIN2A(c0, c1, wa[2], wa[3]);
        if (l < 16) { zb[2 * 16 + l] = c0[0]; zb[3 * 16 + l] = c1[0]; }
        CHAIN1V(c0, lw);                               // tile 13
        if (l < 16) zb[13 * 16 + l] = c0[0];

        STAGE(2)
        CHAIN2A(c0, c1, wa[4], wa[5]);
        if (l < 16) { zb[4 * 16 + l] = c0[0]; zb[5 * 16 + l] = c1[0]; }
        CHAIN1V(c0, lw);                               // tile 14
        if (l < 16) zb[14 * 16 + l] = c0[0];

        STAGE(3)
        CHAIN2A(c0, c1, wa[6], wa[7]);
        if (l < 16) { zb[6 * 16 + l] = c0[0]; zb[7 * 16 + l] = c1[0]; }
        CHAIN1V(c0, lw);                               // tile 15
        if (l < 16) zb[15 * 16 + l] = c0[0];

        CHAIN2V(c0, c1, wr[0], wr[1]);
        if (l < 16) { zb[8 * 16 + l] = c0[0]; zb[9 * 16 + l] = c1[0]; }
        CHAIN2V(c0, c1, wr[2], wr[3]);
        if (l < 16) { zb[10 * 16 + l] = c0[0]; zb[11 * 16 + l] = c1[0]; }

        __syncthreads();

        // elementwise recurrence: thread tid = hidden unit h, all 4 gates
        float z0 = zbuf[tid]       + (float)xv[0];
        float z1 = zbuf[256 + tid] + (float)xv[1];
        float z2 = zbuf[512 + tid] + (float)xv[2];
        float z3 = zbuf[768 + tid] + (float)xv[3];
        float fg  = sigm(z0);
        float pg  = sigm(z1);
        float ptg = tanh_(z2);
        float og  = sigm(z3);
        longv  = fg * longv + pg * ptg;
        shortv = tanh_(longv) * og;
        sbuf[tid] = (__bf16)shortv;
        __syncthreads();
        xv = xn;
    }

    state_s[(b << 8) + tid] = shortv;
    state_l[(b << 8) + tid] = longv;
    if (last) {
        out[(b << 8) + tid]         = shortv;   // short
        out[65536 + (b << 8) + tid] = longv;    // long
    }
}

// ---------------------------------------------------------------------------
extern "C" void kernel_launch(void* const* d_in, const int* in_sizes, int n_in,
                              void* d_out, int out_size, void* d_ws, size_t ws_size,
                              hipStream_t stream) {
    const float* x   = (const float*)d_in[0];
    const float* Wfh = (const float*)d_in[1];
    const float* Wfx = (const float*)d_in[2];
    const float* bf_ = (const float*)d_in[3];
    const float* Wph = (const float*)d_in[4];
    const float* Wpx = (const float*)d_in[5];
    const float* bp_ = (const float*)d_in[6];
    const float* Wth = (const float*)d_in[7];
    const float* Wtx = (const float*)d_in[8];
    const float* bt_ = (const float*)d_in[9];
    const float* Woh = (const float*)d_in[10];
    const float* Wox = (const float*)d_in[11];
    const float* bo_ = (const float*)d_in[12];
    float* out = (float*)d_out;

    const size_t WHB = (size_t)262144 * 2;   // 512 KB prepacked Wh
    const size_t WXB = (size_t)131072 * 2;   // 256 KB prepacked Wx
    const size_t STB = (size_t)65536 * 4;    // 256 KB per state array

    // largest time-chunk whose bf16 XP buffer fits the workspace
    int Tc = 1024, tcsh = 10;
    while (Tc > 8) {
        size_t need = (size_t)256 * Tc * 1024 * 2 + WHB + WXB + 2 * STB;
        if (need <= ws_size) break;
        Tc >>= 1; tcsh--;
    }

    char* wsb = (char*)d_ws;
    __bf16* xpbuf   = (__bf16*)wsb;
    char*   rest    = wsb + (size_t)256 * Tc * 1024 * 2;
    __bf16* whfrag  = (__bf16*)rest;
    __bf16* wxfrag  = (__bf16*)(rest + WHB);
    float*  state_s = (float*)(rest + WHB + WXB);
    float*  state_l = (float*)(rest + WHB + WXB + STB);

    prep_wh<<<1024, 256, 0, stream>>>(Wfh, Wph, Wth, Woh, whfrag);
    prep_wx<<<512, 256, 0, stream>>>(Wfx, Wpx, Wtx, Wox, wxfrag);

    const int nchunk = 1024 / Tc;
    for (int c = 0; c < nchunk; c++) {
        xproj_gemm<<<dim3(2 * Tc, 8), 256, 0, stream>>>(
            x, wxfrag, bf_, bp_, bt_, bo_, xpbuf, Tc, tcsh, c);
        recur<<<256, 256, 0, stream>>>(
            xpbuf, whfrag, state_s, state_l, out, Tc, tcsh,
            (c == 0) ? 1 : 0, (c == nchunk - 1) ? 1 : 0);
    }
}

// Round 6
// 2468.753 us; speedup vs baseline: 9.2371x; 1.1602x over previous
//
#include <hip/hip_runtime.h>
#include <cstdint>
#include <cstddef>

typedef __bf16 bf16x8 __attribute__((ext_vector_type(8)));
typedef __bf16 bf16x4 __attribute__((ext_vector_type(4)));
typedef float  f32x4  __attribute__((ext_vector_type(4)));

// intrinsic MFMA for the xproj GEMM (compiler-scheduled)
#define MFMA16(a, b, c) __builtin_amdgcn_mfma_f32_16x16x32_bf16((a), (b), (c), 0, 0, 0)

// ---------------------------------------------------------------------------
// Self-contained MFMA chain asm blocks for the recurrence (round-5-proven).
//  - SrcC of the first MFMA is a loop-invariant zero register (zz): no
//    VALU-init -> MFMA SrcC hazard inside the loop.
//  - All MFMAs of a chain live in ONE asm block: scheduler cannot reorder.
//  - Trailing s_nop 7 x2 INSIDE the block: any subsequent reader is >=16
//    cycles after the last MFMA (dst-write hazard safe).
//  - "=&v" early-clobber: accumulators never alias a/w/zz inputs.
// ---------------------------------------------------------------------------
#define MF "v_mfma_f32_16x16x32_bf16 "
#define CH2_BODY \
    MF "%0, %2, %10, %26\n\t"  MF "%1, %2, %18, %26\n\t" \
    MF "%0, %3, %11, %0\n\t"   MF "%1, %3, %19, %1\n\t"  \
    MF "%0, %4, %12, %0\n\t"   MF "%1, %4, %20, %1\n\t"  \
    MF "%0, %5, %13, %0\n\t"   MF "%1, %5, %21, %1\n\t"  \
    MF "%0, %6, %14, %0\n\t"   MF "%1, %6, %22, %1\n\t"  \
    MF "%0, %7, %15, %0\n\t"   MF "%1, %7, %23, %1\n\t"  \
    MF "%0, %8, %16, %0\n\t"   MF "%1, %8, %24, %1\n\t"  \
    MF "%0, %9, %17, %0\n\t"   MF "%1, %9, %25, %1\n\t"  \
    "s_nop 7\n\ts_nop 7"
#define CH1_BODY \
    MF "%0, %1, %9,  %17\n\t" \
    MF "%0, %2, %10, %0\n\t"  \
    MF "%0, %3, %11, %0\n\t"  \
    MF "%0, %4, %12, %0\n\t"  \
    MF "%0, %5, %13, %0\n\t"  \
    MF "%0, %6, %14, %0\n\t"  \
    MF "%0, %7, %15, %0\n\t"  \
    MF "%0, %8, %16, %0\n\t"  \
    "s_nop 7\n\ts_nop 7"

#define A8(aa)  "v"((aa)[0]), "v"((aa)[1]), "v"((aa)[2]), "v"((aa)[3]), \
                "v"((aa)[4]), "v"((aa)[5]), "v"((aa)[6]), "v"((aa)[7])
#define W8A(W)  "a"((W)[0]), "a"((W)[1]), "a"((W)[2]), "a"((W)[3]), \
                "a"((W)[4]), "a"((W)[5]), "a"((W)[6]), "a"((W)[7])
#define W8V(W)  "v"((W)[0]), "v"((W)[1]), "v"((W)[2]), "v"((W)[3]), \
                "v"((W)[4]), "v"((W)[5]), "v"((W)[6]), "v"((W)[7])

#define CHAIN2A(c0, c1, W0, W1) \
    asm(CH2_BODY : "=&v"(c0), "=&v"(c1) : A8(a), W8A(W0), W8A(W1), "v"(zz))
#define CHAIN2V(c0, c1, W0, W1) \
    asm(CH2_BODY : "=&v"(c0), "=&v"(c1) : A8(a), W8V(W0), W8V(W1), "v"(zz))
#define CHAIN1V(c0, W) \
    asm(CH1_BODY : "=&v"(c0) : A8(a), W8V(W), "v"(zz))

__device__ __forceinline__ float sigm(float x) {
    return 1.f / (1.f + __expf(-x));
}
__device__ __forceinline__ float tanh_(float x) {
    // tanh(x) = 1 - 2/(e^{2x}+1); expf overflow -> inf -> 1/inf=0 -> 1 (graceful)
    return 1.f - 2.f / (__expf(2.f * x) + 1.f);
}

// ---------------------------------------------------------------------------
// Repack the four H-recurrence weights (256x256 fp32, W[k][h]) into bf16 MFMA
// B-fragment order for 16x16x32_bf16 (layout verified end-to-end round 2):
//   o = ((nt*8 + kb)*64 + lane)*8 + j ;  n = nt*16+(lane&15) = g*256+h ;
//   k = kb*32 + (lane>>4)*8 + j
// ---------------------------------------------------------------------------
__global__ void prep_wh(const float* __restrict__ Wf, const float* __restrict__ Wp,
                        const float* __restrict__ Wt, const float* __restrict__ Wo,
                        __bf16* __restrict__ out) {
    int o  = blockIdx.x * 256 + threadIdx.x;   // 262144 total
    int j  = o & 7;
    int l  = (o >> 3) & 63;
    int kb = (o >> 9) & 7;
    int nt = o >> 12;                          // 0..63
    int n  = nt * 16 + (l & 15);
    int g  = n >> 8, h = n & 255;
    int k  = kb * 32 + (l >> 4) * 8 + j;       // 0..255
    const float* W = (g == 0) ? Wf : (g == 1) ? Wp : (g == 2) ? Wt : Wo;
    out[o] = (__bf16)W[k * 256 + h];
}

// Same for the x-projection weights (128x256), K=128 -> kb 0..3
__global__ void prep_wx(const float* __restrict__ Wf, const float* __restrict__ Wp,
                        const float* __restrict__ Wt, const float* __restrict__ Wo,
                        __bf16* __restrict__ out) {
    int o  = blockIdx.x * 256 + threadIdx.x;   // 131072 total
    int j  = o & 7;
    int l  = (o >> 3) & 63;
    int kb = (o >> 9) & 3;
    int nt = o >> 11;                          // 0..63
    int n  = nt * 16 + (l & 15);
    int g  = n >> 8, h = n & 255;
    int k  = kb * 32 + (l >> 4) * 8 + j;       // 0..127
    const float* W = (g == 0) ? Wf : (g == 1) ? Wp : (g == 2) ? Wt : Wo;
    out[o] = (__bf16)W[k * 256 + h];
}

// ---------------------------------------------------------------------------
// Chunked x-projection GEMM. Chunk c covers time steps [c*Tc, (c+1)*Tc).
// Row r = b*Tc + tc. Output N-MAJOR: XP[r][n] (bf16, bias included),
// n = g*256+h. Stores are 32-B contiguous runs per 16-lane group and each
// 128-B line is completed by one wave in one epilogue (round-2-proven
// pattern; the round-5 transposed layout caused ~1.5 ms of HBM RMW).
// ---------------------------------------------------------------------------
__global__ __launch_bounds__(256) void xproj_gemm(
        const float* __restrict__ x, const __bf16* __restrict__ wxfrag,
        const float* __restrict__ bf, const float* __restrict__ bp,
        const float* __restrict__ bt, const float* __restrict__ bo,
        __bf16* __restrict__ xp, int Tc, int tcsh, int chunk) {
    __shared__ __align__(16) __bf16 As[128 * 128];   // 32 KB
    const int tid = threadIdx.x;
    const int m0  = blockIdx.x * 128;
    const int by  = blockIdx.y;                      // 0..7 (N-tile of 128)
    const int c0  = chunk * Tc;

    // stage A: 128 chunk-rows x 128 cols, fp32 -> bf16
#pragma unroll
    for (int i = 0; i < 16; i++) {
        int f   = i * 256 + tid;
        int row = f >> 5;
        int c4  = (f & 31) * 4;
        int r   = m0 + row;
        int b   = r >> tcsh;
        int tc  = r & (Tc - 1);
        float4 v = *reinterpret_cast<const float4*>(
            x + ((size_t)b * 1024 + (size_t)(c0 + tc)) * 128 + c4);
        __bf16 w0 = (__bf16)v.x, w1 = (__bf16)v.y, w2 = (__bf16)v.z, w3 = (__bf16)v.w;
        bf16x4 w = {w0, w1, w2, w3};
        *reinterpret_cast<bf16x4*>(&As[row * 128 + c4]) = w;
    }
    __syncthreads();

    const int wv = tid >> 6, l = tid & 63, lm = l & 15, lk = l >> 4;
    const bf16x8* bfr = reinterpret_cast<const bf16x8*>(wxfrag);

    f32x4 acc[2][8];
#pragma unroll
    for (int a = 0; a < 2; a++)
#pragma unroll
        for (int c = 0; c < 8; c++) acc[a][c] = (f32x4){0.f, 0.f, 0.f, 0.f};

#pragma unroll
    for (int kb = 0; kb < 4; kb++) {
        bf16x8 afr[2];
#pragma unroll
        for (int tr = 0; tr < 2; tr++)
            afr[tr] = *reinterpret_cast<const bf16x8*>(
                &As[(wv * 32 + tr * 16 + lm) * 128 + kb * 32 + lk * 8]);
#pragma unroll
        for (int tc = 0; tc < 8; tc++) {
            int nt = by * 8 + tc;
            bf16x8 bq = bfr[(nt * 4 + kb) * 64 + l];
            acc[0][tc] = MFMA16(afr[0], bq, acc[0][tc]);
            acc[1][tc] = MFMA16(afr[1], bq, acc[1][tc]);
        }
    }

    const int g = by >> 1;
    const float* bias = (g == 0) ? bf : (g == 1) ? bp : (g == 2) ? bt : bo;
#pragma unroll
    for (int tc = 0; tc < 8; tc++) {
        int n   = by * 128 + tc * 16 + lm;
        float bv = bias[n & 255];
#pragma unroll
        for (int tr = 0; tr < 2; tr++) {
#pragma unroll
            for (int r = 0; r < 4; r++) {
                int row = m0 + wv * 32 + tr * 16 + lk * 4 + r;
                xp[(size_t)row * 1024 + n] = (__bf16)(acc[tr][tc][r] + bv);
            }
        }
    }
}

// ---------------------------------------------------------------------------
// Persistent recurrence over one time chunk. 256 blocks (1 batch row / CU),
// 256 threads (4 waves, 1/SIMD). Wave g = gate g = 16 N-tiles:
//   tiles 0..7  : weights in AGPRs (256/lane), "a" asm operands
//   tiles 8..11 : weights in VGPRs (128/lane), "v" asm operands
//   tiles 12..15: weights in LDS (128 KB), staged 1 tile at a time,
//                 interleaved with the AGPR chains to hide ds_read latency.
// M=1-padded MFMA: A = short broadcast to all 16 M-rows; D row 0 real.
// XP loads (4 scalar bf16, n-major) software-pipelined one step ahead.
// Per-SIMD issue floor: 128 MFMA x ~16 cyc = 2064 cyc/step; measured 2350.
// ---------------------------------------------------------------------------
__global__ __launch_bounds__(256, 1) void recur(
        const __bf16* __restrict__ xp, const __bf16* __restrict__ whfrag,
        float* __restrict__ state_s, float* __restrict__ state_l,
        float* __restrict__ out, int Tc, int tcsh, int first, int last) {
    __shared__ __align__(16) bf16x8 wlds[4 * 4 * 8 * 64];   // 131072 B
    __shared__ float  zbuf[1024];                           //   4096 B
    __shared__ __bf16 sbuf[256];                            //    512 B

    const int tid = threadIdx.x, wv = tid >> 6, l = tid & 63, lk = l >> 4;
    const int b = blockIdx.x;
    const bf16x8* wf = reinterpret_cast<const bf16x8*>(whfrag);

    // AGPR weight tiles 0..7 (64 frags = 256 AGPRs/lane)
    bf16x8 wa[8][8];
#pragma unroll
    for (int t = 0; t < 8; t++)
#pragma unroll
        for (int kb = 0; kb < 8; kb++)
            wa[t][kb] = wf[((wv * 16 + t) * 8 + kb) * 64 + l];
    // VGPR weight tiles 8..11 (32 frags = 128 VGPRs/lane)
    bf16x8 wr[4][8];
#pragma unroll
    for (int t = 0; t < 4; t++)
#pragma unroll
        for (int kb = 0; kb < 8; kb++)
            wr[t][kb] = wf[((wv * 16 + 8 + t) * 8 + kb) * 64 + l];
    // LDS weight tiles 12..15
#pragma unroll
    for (int t = 0; t < 4; t++)
#pragma unroll
        for (int kb = 0; kb < 8; kb++)
            wlds[((wv * 4 + t) * 8 + kb) * 64 + l] =
                wf[((wv * 16 + 12 + t) * 8 + kb) * 64 + l];

    float shortv, longv;
    if (first) { shortv = 0.f; longv = 0.f; }
    else       { shortv = state_s[(b << 8) + tid]; longv = state_l[(b << 8) + tid]; }
    sbuf[tid] = (__bf16)shortv;
    __syncthreads();

    const bf16x8* wldsw = wlds + (size_t)wv * 4 * 8 * 64;
    float* zb = zbuf + wv * 256;
    const __bf16* xpt = xp + ((size_t)b << (tcsh + 10)) + tid;

    const f32x4 zz = {0.f, 0.f, 0.f, 0.f};   // loop-invariant SrcC zero

    // prefetch step 0 (n-major: gate g at offset g*256)
    __bf16 xv0 = xpt[0], xv1 = xpt[256], xv2 = xpt[512], xv3 = xpt[768];

#define STAGE(lt) \
    _Pragma("unroll") for (int kb = 0; kb < 8; kb++) lw[kb] = wldsw[((lt) * 8 + kb) * 64 + l];

    for (int t = 0; t < Tc; t++) {
        // A-fragments: broadcast short into every M-row
        bf16x8 a[8];
#pragma unroll
        for (int kb = 0; kb < 8; kb++)
            a[kb] = *reinterpret_cast<const bf16x8*>(&sbuf[kb * 32 + lk * 8]);

        // prefetch next step's XP (consumed next iteration)
        size_t tn = (size_t)((t + 1 < Tc) ? t + 1 : t) * 1024;
        __bf16 xn0 = xpt[tn], xn1 = xpt[tn + 256], xn2 = xpt[tn + 512], xn3 = xpt[tn + 768];

        bf16x8 lw[8];
        f32x4 c0, c1;

        STAGE(0)
        CHAIN2A(c0, c1, wa[0], wa[1]);
        if (l < 16) { zb[0 * 16 + l] = c0[0]; zb[1 * 16 + l] = c1[0]; }
        CHAIN1V(c0, lw);                               // tile 12
        if (l < 16) zb[12 * 16 + l] = c0[0];

        STAGE(1)
        CHAIN2A(c0, c1, wa[2], wa[3]);
        if (l < 16) { zb[2 * 16 + l] = c0[0]; zb[3 * 16 + l] = c1[0]; }
        CHAIN1V(c0, lw);                               // tile 13
        if (l < 16) zb[13 * 16 + l] = c0[0];

        STAGE(2)
        CHAIN2A(c0, c1, wa[4], wa[5]);
        if (l < 16) { zb[4 * 16 + l] = c0[0]; zb[5 * 16 + l] = c1[0]; }
        CHAIN1V(c0, lw);                               // tile 14
        if (l < 16) zb[14 * 16 + l] = c0[0];

        STAGE(3)
        CHAIN2A(c0, c1, wa[6], wa[7]);
        if (l < 16) { zb[6 * 16 + l] = c0[0]; zb[7 * 16 + l] = c1[0]; }
        CHAIN1V(c0, lw);                               // tile 15
        if (l < 16) zb[15 * 16 + l] = c0[0];

        CHAIN2V(c0, c1, wr[0], wr[1]);
        if (l < 16) { zb[8 * 16 + l] = c0[0]; zb[9 * 16 + l] = c1[0]; }
        CHAIN2V(c0, c1, wr[2], wr[3]);
        if (l < 16) { zb[10 * 16 + l] = c0[0]; zb[11 * 16 + l] = c1[0]; }

        __syncthreads();

        // elementwise recurrence: thread tid = hidden unit h, all 4 gates
        float z0 = zbuf[tid]       + (float)xv0;
        float z1 = zbuf[256 + tid] + (float)xv1;
        float z2 = zbuf[512 + tid] + (float)xv2;
        float z3 = zbuf[768 + tid] + (float)xv3;
        float fg  = sigm(z0);
        float pg  = sigm(z1);
        float ptg = tanh_(z2);
        float og  = sigm(z3);
        longv  = fg * longv + pg * ptg;
        shortv = tanh_(longv) * og;
        sbuf[tid] = (__bf16)shortv;
        __syncthreads();
        xv0 = xn0; xv1 = xn1; xv2 = xn2; xv3 = xn3;
    }

    state_s[(b << 8) + tid] = shortv;
    state_l[(b << 8) + tid] = longv;
    if (last) {
        out[(b << 8) + tid]         = shortv;   // short
        out[65536 + (b << 8) + tid] = longv;    // long
    }
}

// ---------------------------------------------------------------------------
extern "C" void kernel_launch(void* const* d_in, const int* in_sizes, int n_in,
                              void* d_out, int out_size, void* d_ws, size_t ws_size,
                              hipStream_t stream) {
    const float* x   = (const float*)d_in[0];
    const float* Wfh = (const float*)d_in[1];
    const float* Wfx = (const float*)d_in[2];
    const float* bf_ = (const float*)d_in[3];
    const float* Wph = (const float*)d_in[4];
    const float* Wpx = (const float*)d_in[5];
    const float* bp_ = (const float*)d_in[6];
    const float* Wth = (const float*)d_in[7];
    const float* Wtx = (const float*)d_in[8];
    const float* bt_ = (const float*)d_in[9];
    const float* Woh = (const float*)d_in[10];
    const float* Wox = (const float*)d_in[11];
    const float* bo_ = (const float*)d_in[12];
    float* out = (float*)d_out;

    const size_t WHB = (size_t)262144 * 2;   // 512 KB prepacked Wh
    const size_t WXB = (size_t)131072 * 2;   // 256 KB prepacked Wx
    const size_t STB = (size_t)65536 * 4;    // 256 KB per state array

    // largest time-chunk whose bf16 XP buffer fits the workspace
    int Tc = 1024, tcsh = 10;
    while (Tc > 8) {
        size_t need = (size_t)256 * Tc * 1024 * 2 + WHB + WXB + 2 * STB;
        if (need <= ws_size) break;
        Tc >>= 1; tcsh--;
    }

    char* wsb = (char*)d_ws;
    __bf16* xpbuf   = (__bf16*)wsb;
    char*   rest    = wsb + (size_t)256 * Tc * 1024 * 2;
    __bf16* whfrag  = (__bf16*)rest;
    __bf16* wxfrag  = (__bf16*)(rest + WHB);
    float*  state_s = (float*)(rest + WHB + WXB);
    float*  state_l = (float*)(rest + WHB + WXB + STB);

    prep_wh<<<1024, 256, 0, stream>>>(Wfh, Wph, Wth, Woh, whfrag);
    prep_wx<<<512, 256, 0, stream>>>(Wfx, Wpx, Wtx, Wox, wxfrag);

    const int nchunk = 1024 / Tc;
    for (int c = 0; c < nchunk; c++) {
        xproj_gemm<<<dim3(2 * Tc, 8), 256, 0, stream>>>(
            x, wxfrag, bf_, bp_, bt_, bo_, xpbuf, Tc, tcsh, c);
        recur<<<256, 256, 0, stream>>>(
            xpbuf, whfrag, state_s, state_l, out, Tc, tcsh,
            (c == 0) ? 1 : 0, (c == nchunk - 1) ? 1 : 0);
    }
}